// Round 8
// baseline (2277.003 us; speedup 1.0000x reference)
//
#include <hip/hip_runtime.h>

// ---- problem constants ----
#define H       128
#define MAXNB   10
#define M_TREE  32768
#define NBOND   262144
#define NATOM   131072
#define FATOM   35
#define FBOND   40
#define FOUT    163
#define KPAD    192
#define NMOLS   4096
#define APM     32
#define TB      64      // bonds per block in mp_step
#define TA      64      // atoms per block in readout
#define CSTRIDE 160     // compressed row slot: 320 B (line-aligned), in u16 units

typedef __bf16 bf16x8 __attribute__((ext_vector_type(8)));
typedef float  f32x4  __attribute__((ext_vector_type(4)));
typedef unsigned int u32x4 __attribute__((ext_vector_type(4)));

__device__ __forceinline__ unsigned short f32_to_bf16(float f) {
  unsigned int u = __float_as_uint(f);
  u += 0x7FFFu + ((u >> 16) & 1u);   // RNE
  return (unsigned short)(u >> 16);
}
__device__ __forceinline__ float bf16u_to_f32(unsigned short h) {
  return __uint_as_float(((unsigned int)h) << 16);
}

// interleave bits: e -> even positions, o -> odd
__device__ __forceinline__ unsigned long long mort2(unsigned int e, unsigned int o) {
  unsigned long long x = e, y = o;
  x = (x | (x << 16)) & 0x0000FFFF0000FFFFull;
  x = (x | (x << 8))  & 0x00FF00FF00FF00FFull;
  x = (x | (x << 4))  & 0x0F0F0F0F0F0F0F0Full;
  x = (x | (x << 2))  & 0x3333333333333333ull;
  x = (x | (x << 1))  & 0x5555555555555555ull;
  y = (y | (y << 16)) & 0x0000FFFF0000FFFFull;
  y = (y | (y << 8))  & 0x00FF00FF00FF00FFull;
  y = (y | (y << 4))  & 0x0F0F0F0F0F0F0F0Full;
  y = (y | (y << 2))  & 0x3333333333333333ull;
  y = (y | (y << 1))  & 0x5555555555555555ull;
  return x | (y << 1);
}

// read compressed row: returns packed bf16 pair for cols (2*li, 2*li+1)
__device__ __forceinline__ unsigned int crow_read(const unsigned short* __restrict__ rp, int li) {
  u32x4 h = *(const u32x4*)rp;
  unsigned long long bm0 = (unsigned long long)h.x | ((unsigned long long)h.y << 32);
  unsigned long long bm1 = (unsigned long long)h.z | ((unsigned long long)h.w << 32);
  const bool hi = li >= 32;
  unsigned long long bm = hi ? bm1 : bm0;
  int base = hi ? (int)__popcll(bm0) : 0;
  int sh = (li & 31) * 2;
  int pos = base + (int)__popcll(bm & ((1ull << sh) - 1ull));
  unsigned int p0 = (unsigned int)((bm >> sh) & 1ull);
  unsigned int p1 = (unsigned int)((bm >> (sh + 1)) & 1ull);
  unsigned short w0 = rp[8 + pos];         // always in-bounds (slot 320 B)
  unsigned short w1 = rp[8 + pos + 1];
  unsigned short v0 = p0 ? w0 : (unsigned short)0;
  unsigned short v1 = p1 ? (p0 ? w1 : w0) : (unsigned short)0;
  return (unsigned int)v0 | ((unsigned int)v1 << 16);
}

// write compressed row: lane li provides bf16 values for cols (2*li, 2*li+1)
__device__ __forceinline__ void crow_write(unsigned short* __restrict__ wp, int li,
                                           unsigned short v0, unsigned short v1) {
  unsigned long long be = __ballot(v0 != 0);   // bit li = col 2*li
  unsigned long long bo = __ballot(v1 != 0);   // bit li = col 2*li+1
  unsigned long long obm0 = mort2((unsigned int)be, (unsigned int)bo);
  unsigned long long obm1 = mort2((unsigned int)(be >> 32), (unsigned int)(bo >> 32));
  const bool hi = li >= 32;
  unsigned long long obm = hi ? obm1 : obm0;
  int base = hi ? (int)__popcll(obm0) : 0;
  int sh = (li & 31) * 2;
  int pos = base + (int)__popcll(obm & ((1ull << sh) - 1ull));
  if (li == 0) {
    u32x4 hd;
    hd.x = (unsigned int)obm0; hd.y = (unsigned int)(obm0 >> 32);
    hd.z = (unsigned int)obm1; hd.w = (unsigned int)(obm1 >> 32);
    *(u32x4*)wp = hd;
  }
  if (v0) wp[8 + pos] = v0;
  if (v1) wp[8 + pos + (v0 ? 1 : 0)] = v1;
}

// ---- prep: bf16 conversions + padded weight layouts (tmsg stays dense) ----
__global__ __launch_bounds__(256) void prep(const float* __restrict__ tm,
                                            const float* __restrict__ wh,
                                            const float* __restrict__ wo,
                                            const float* __restrict__ wi,
                                            unsigned short* __restrict__ tmsg,
                                            unsigned short* __restrict__ whb,
                                            unsigned short* __restrict__ wob,
                                            unsigned short* __restrict__ wib) {
  int i = blockIdx.x * 256 + threadIdx.x;
  const int n1 = M_TREE * H;
  const int n2 = H * H;
  const int n3 = H * KPAD;
  const int n4 = H * 64;
  if (i < n1) { tmsg[i] = f32_to_bf16(__builtin_nontemporal_load(tm + i)); return; }
  int j = i - n1;
  if (j < n2) { whb[j] = f32_to_bf16(wh[j]); return; }
  int k = j - n2;
  if (k < n3) {
    int g = k / KPAD, kk = k - g * KPAD;
    float v = 0.f;
    if (kk < 35)                   v = wo[g * FOUT + kk];
    else if (kk >= 36 && kk < 164) v = wo[g * FOUT + kk - 1];
    wob[k] = f32_to_bf16(v);
    return;
  }
  int m = k - n3;
  if (m < n4) {
    int g = m / 64, kk = m - g * 64;
    wib[m] = (kk < FBOND) ? f32_to_bf16(wi[g * FBOND + kk]) : (unsigned short)0;
  }
}

// ---- h0 = relu(bond_feats @ W_i^T), 64 bonds/block, writes COMPRESSED ch0 ----
__global__ __launch_bounds__(256, 4) void wi_gemm(const float* __restrict__ bond_feats,
                                                  const unsigned short* __restrict__ wib,
                                                  unsigned short* __restrict__ ch0) {
  __shared__ unsigned short sF[64][72];
  __shared__ unsigned short sStage[64][136];
  const int t = threadIdx.x;
  const int lane = t & 63;
  const int wave = t >> 6;
  const int n16 = lane & 15;
  const int quad = lane >> 4;
  const int b0 = blockIdx.x * 64;

  for (int i = t; i < 64 * FBOND; i += 256) {
    int b = i / FBOND, f = i - b * FBOND;
    sF[b][f] = f32_to_bf16(__builtin_nontemporal_load(bond_feats + b0 * FBOND + i));
  }
  for (int i = t; i < 64 * 24; i += 256) {
    int b = i / 24, c = 40 + i - b * 24;
    sF[b][c] = 0;
  }
  bf16x8 Bf[2][2];
#pragma unroll
  for (int kt = 0; kt < 2; ++kt)
#pragma unroll
    for (int nt = 0; nt < 2; ++nt)
      Bf[kt][nt] = *(const bf16x8*)(wib + ((wave * 2 + nt) * 16 + n16) * 64 + kt * 32 + quad * 8);
  __syncthreads();

  f32x4 acc[4][2];
  f32x4 zero = {0.f, 0.f, 0.f, 0.f};
#pragma unroll
  for (int mt = 0; mt < 4; ++mt) { acc[mt][0] = zero; acc[mt][1] = zero; }
#pragma unroll
  for (int kt = 0; kt < 2; ++kt)
#pragma unroll
    for (int mt = 0; mt < 4; ++mt) {
      bf16x8 av = *(const bf16x8*)&sF[mt * 16 + n16][kt * 32 + quad * 8];
      acc[mt][0] = __builtin_amdgcn_mfma_f32_16x16x32_bf16(av, Bf[kt][0], acc[mt][0], 0, 0, 0);
      acc[mt][1] = __builtin_amdgcn_mfma_f32_16x16x32_bf16(av, Bf[kt][1], acc[mt][1], 0, 0, 0);
    }
  // stage relu'd bf16
#pragma unroll
  for (int mt = 0; mt < 4; ++mt)
#pragma unroll
    for (int nt = 0; nt < 2; ++nt) {
      const int col = (wave * 2 + nt) * 16 + n16;
#pragma unroll
      for (int r = 0; r < 4; ++r)
        sStage[mt * 16 + quad * 4 + r][col] = f32_to_bf16(fmaxf(acc[mt][nt][r], 0.f));
    }
  __syncthreads();
  for (int r = wave; r < 64; r += 4) {
    unsigned int a = *(const unsigned int*)&sStage[r][2 * lane];
    crow_write(ch0 + (size_t)(b0 + r) * CSTRIDE, lane,
               (unsigned short)a, (unsigned short)(a >> 16));
  }
}

// ---- one MP round over compressed tables ----
__global__ __launch_bounds__(256, 5) void mp_step(const unsigned short* __restrict__ gin,
                                                  unsigned short* __restrict__ gout,
                                                  const unsigned short* __restrict__ ch0,
                                                  const unsigned short* __restrict__ tmsg,
                                                  const int* __restrict__ bond_graph,
                                                  const unsigned short* __restrict__ whb) {
  __shared__ unsigned short snei[TB][136];   // 17408 B
  __shared__ int sBG[TB * MAXNB];            //  2560 B
  const int t = threadIdx.x;
  const int lane = t & 63;
  const int wave = t >> 6;
  const int n16 = lane & 15;
  const int quad = lane >> 4;
  const int b0 = blockIdx.x * TB;

  for (int i = t; i < TB * MAXNB; i += 256) sBG[i] = bond_graph[b0 * MAXNB + i];
  __syncthreads();

  // gather: wave-uniform indices; tree -> dense tmsg, graph -> compressed gin
  for (int lb = wave * 2; lb < TB; lb += 8) {
#pragma unroll
    for (int p = 0; p < 2; ++p) {
      const int* ig = &sBG[(lb + p) * MAXNB];
      float a0 = 0.f, a1 = 0.f;
#pragma unroll
      for (int j = 0; j < MAXNB; ++j) {
        int idx = __builtin_amdgcn_readfirstlane(ig[j]);
        unsigned int u;
        if (idx < M_TREE) {
          u = *(const unsigned int*)(tmsg + (size_t)idx * H + 2 * lane);
        } else {
          u = crow_read(gin + (size_t)(idx - M_TREE) * CSTRIDE, lane);
        }
        a0 += __uint_as_float(u << 16);
        a1 += __uint_as_float(u & 0xFFFF0000u);
      }
      unsigned int packed = ((unsigned int)f32_to_bf16(a1) << 16) | (unsigned int)f32_to_bf16(a0);
      *(unsigned int*)&snei[lb + p][2 * lane] = packed;
    }
  }

  bf16x8 Bf[4][2];
#pragma unroll
  for (int kt = 0; kt < 4; ++kt)
#pragma unroll
    for (int nt = 0; nt < 2; ++nt)
      Bf[kt][nt] = *(const bf16x8*)(whb + ((wave * 2 + nt) * 16 + n16) * H + kt * 32 + quad * 8);
  __syncthreads();

  f32x4 acc[4][2];
  f32x4 zero = {0.f, 0.f, 0.f, 0.f};
#pragma unroll
  for (int mt = 0; mt < 4; ++mt) { acc[mt][0] = zero; acc[mt][1] = zero; }
#pragma unroll
  for (int kt = 0; kt < 4; ++kt)
#pragma unroll
    for (int mt = 0; mt < 4; ++mt) {
      bf16x8 av = *(const bf16x8*)&snei[mt * 16 + n16][kt * 32 + quad * 8];
      acc[mt][0] = __builtin_amdgcn_mfma_f32_16x16x32_bf16(av, Bf[kt][0], acc[mt][0], 0, 0, 0);
      acc[mt][1] = __builtin_amdgcn_mfma_f32_16x16x32_bf16(av, Bf[kt][1], acc[mt][1], 0, 0, 0);
    }
  __syncthreads();

  // stage acc -> snei (bf16, pre-add)
#pragma unroll
  for (int mt = 0; mt < 4; ++mt)
#pragma unroll
    for (int nt = 0; nt < 2; ++nt) {
      const int col = (wave * 2 + nt) * 16 + n16;
#pragma unroll
      for (int r = 0; r < 4; ++r)
        snei[mt * 16 + quad * 4 + r][col] = f32_to_bf16(acc[mt][nt][r]);
    }
  __syncthreads();

  // epilogue: decompress ch0 row, add, relu, compressed write
  for (int r = wave; r < TB; r += 4) {
    unsigned int a = *(const unsigned int*)&snei[r][2 * lane];
    unsigned int hh = crow_read(ch0 + (size_t)(b0 + r) * CSTRIDE, lane);
    float v0f = fmaxf(bf16u_to_f32((unsigned short)hh) + bf16u_to_f32((unsigned short)a), 0.f);
    float v1f = fmaxf(bf16u_to_f32((unsigned short)(hh >> 16)) + bf16u_to_f32((unsigned short)(a >> 16)), 0.f);
    crow_write(gout + (size_t)(b0 + r) * CSTRIDE, lane, f32_to_bf16(v0f), f32_to_bf16(v1f));
  }
}

// ---- readout: 64 atoms (2 mols)/block, compressed gather, MFMA over K=192 ----
__global__ __launch_bounds__(256, 4) void readout(const float* __restrict__ atom_feats,
                                                  const unsigned short* __restrict__ gm,
                                                  const unsigned short* __restrict__ tmsg,
                                                  const int* __restrict__ atom_graph,
                                                  const unsigned short* __restrict__ wob,
                                                  const float* __restrict__ b_o,
                                                  float* __restrict__ out) {
  __shared__ unsigned short sA[TA][200];
  __shared__ int sAG[TA * MAXNB];
  const int t = threadIdx.x;
  const int lane = t & 63;
  const int wave = t >> 6;
  const int n16 = lane & 15;
  const int quad = lane >> 4;
  const int blk = blockIdx.x;
  const int abase = blk * TA;

  for (int i = t; i < TA * MAXNB; i += 256)
    sAG[i] = __builtin_nontemporal_load(atom_graph + abase * MAXNB + i);
  for (int i = t; i < TA * FATOM; i += 256) {
    int a = i / FATOM, f = i - a * FATOM;
    sA[a][f] = f32_to_bf16(__builtin_nontemporal_load(atom_feats + abase * FATOM + i));
  }
  if (t < TA) sA[t][35] = 0;
  for (int i = t; i < TA * 28; i += 256) {
    int a = i / 28, c = 164 + i - a * 28;
    sA[a][c] = 0;
  }
  __syncthreads();

  for (int la = wave * 2; la < TA; la += 8) {
#pragma unroll
    for (int p = 0; p < 2; ++p) {
      const int* ig = &sAG[(la + p) * MAXNB];
      float a0 = 0.f, a1 = 0.f;
#pragma unroll
      for (int j = 0; j < MAXNB; ++j) {
        int idx = __builtin_amdgcn_readfirstlane(ig[j]);
        unsigned int u;
        if (idx < M_TREE) {
          u = *(const unsigned int*)(tmsg + (size_t)idx * H + 2 * lane);
        } else {
          u = crow_read(gm + (size_t)(idx - M_TREE) * CSTRIDE, lane);
        }
        a0 += __uint_as_float(u << 16);
        a1 += __uint_as_float(u & 0xFFFF0000u);
      }
      unsigned int packed = ((unsigned int)f32_to_bf16(a1) << 16) | (unsigned int)f32_to_bf16(a0);
      *(unsigned int*)&sA[la + p][36 + 2 * lane] = packed;
    }
  }

  bf16x8 Bf[6][2];
#pragma unroll
  for (int kt = 0; kt < 6; ++kt)
#pragma unroll
    for (int nt = 0; nt < 2; ++nt)
      Bf[kt][nt] = *(const bf16x8*)(wob + ((wave * 2 + nt) * 16 + n16) * KPAD + kt * 32 + quad * 8);
  __syncthreads();

  f32x4 acc[4][2];
  f32x4 zero = {0.f, 0.f, 0.f, 0.f};
#pragma unroll
  for (int mt = 0; mt < 4; ++mt) { acc[mt][0] = zero; acc[mt][1] = zero; }
#pragma unroll
  for (int kt = 0; kt < 6; ++kt)
#pragma unroll
    for (int mt = 0; mt < 4; ++mt) {
      bf16x8 av = *(const bf16x8*)&sA[mt * 16 + n16][kt * 32 + quad * 8];
      acc[mt][0] = __builtin_amdgcn_mfma_f32_16x16x32_bf16(av, Bf[kt][0], acc[mt][0], 0, 0, 0);
      acc[mt][1] = __builtin_amdgcn_mfma_f32_16x16x32_bf16(av, Bf[kt][1], acc[mt][1], 0, 0, 0);
    }

  float bo[2] = { b_o[(wave * 2) * 16 + n16], b_o[(wave * 2 + 1) * 16 + n16] };
  float part[2][2] = {{0.f,0.f},{0.f,0.f}};
#pragma unroll
  for (int mt = 0; mt < 4; ++mt)
#pragma unroll
    for (int nt = 0; nt < 2; ++nt)
#pragma unroll
      for (int r = 0; r < 4; ++r)
        part[mt >> 1][nt] += fmaxf(acc[mt][nt][r] + bo[nt], 0.f);
#pragma unroll
  for (int mol = 0; mol < 2; ++mol)
#pragma unroll
    for (int nt = 0; nt < 2; ++nt) {
      float p = part[mol][nt];
      p += __shfl_xor(p, 16);
      p += __shfl_xor(p, 32);
      if (lane < 16)
        out[(blk * 2 + mol) * H + (wave * 2 + nt) * 16 + lane] = p * (1.0f / APM);
    }
}

extern "C" void kernel_launch(void* const* d_in, const int* in_sizes, int n_in,
                              void* d_out, int out_size, void* d_ws, size_t ws_size,
                              hipStream_t stream) {
  (void)in_sizes; (void)n_in; (void)out_size; (void)ws_size;
  const float* atom_feats   = (const float*)d_in[0];
  const float* bond_feats   = (const float*)d_in[1];
  const float* tree_message = (const float*)d_in[2];
  const int*   atom_graph   = (const int*)d_in[3];
  const int*   bond_graph   = (const int*)d_in[4];
  const float* W_i = (const float*)d_in[6];
  const float* W_h = (const float*)d_in[7];
  const float* W_o = (const float*)d_in[8];
  const float* b_o = (const float*)d_in[9];
  float* out = (float*)d_out;

  char* ws = (char*)d_ws;
  unsigned short* tmsg = (unsigned short*)(ws);                    //  8,388,608 B
  unsigned short* whb  = (unsigned short*)(ws + 8388608);          //     32,768 B
  unsigned short* wob  = (unsigned short*)(ws + 8421376);          //     49,152 B
  unsigned short* wib  = (unsigned short*)(ws + 8470528);          //     16,384 B
  unsigned short* ch0  = (unsigned short*)(ws + 8486912);          // 83,886,080 B (B x 320)
  unsigned short* gmc0 = (unsigned short*)(ws + 92372992);         // 83,886,080 B
  unsigned short* gmc1 = (unsigned short*)(ws + 176259072);        // 83,886,080 B
  // total: 260,145,152 B

  prep<<<16576, 256, 0, stream>>>(tree_message, W_h, W_o, W_i, tmsg, whb, wob, wib);
  wi_gemm<<<NBOND / 64, 256, 0, stream>>>(bond_feats, wib, ch0);
  mp_step<<<NBOND / TB, 256, 0, stream>>>(ch0,  gmc0, ch0, tmsg, bond_graph, whb);
  mp_step<<<NBOND / TB, 256, 0, stream>>>(gmc0, gmc1, ch0, tmsg, bond_graph, whb);
  mp_step<<<NBOND / TB, 256, 0, stream>>>(gmc1, gmc0, ch0, tmsg, bond_graph, whb);
  mp_step<<<NBOND / TB, 256, 0, stream>>>(gmc0, gmc1, ch0, tmsg, bond_graph, whb);
  mp_step<<<NBOND / TB, 256, 0, stream>>>(gmc1, gmc0, ch0, tmsg, bond_graph, whb);
  readout<<<NATOM / TA, 256, 0, stream>>>(atom_feats, gmc0, tmsg, atom_graph, wob, b_o, out);
}

// Round 9
// 819.857 us; speedup vs baseline: 2.7773x; 2.7773x over previous
//
#include <hip/hip_runtime.h>

// ---- problem constants ----
#define H       128
#define MAXNB   10
#define M_TREE  32768
#define NBOND   262144
#define NATOM   131072
#define FATOM   35
#define FBOND   40
#define FOUT    163
#define KPAD    192
#define NMOLS   4096
#define APM     32
#define TB      64      // bonds per block in mp_step
#define TA      64      // atoms per block in readout

typedef __bf16 bf16x8 __attribute__((ext_vector_type(8)));
typedef float  f32x4  __attribute__((ext_vector_type(4)));
typedef unsigned int u32x4 __attribute__((ext_vector_type(4)));

__device__ __forceinline__ unsigned short f32_to_bf16(float f) {
  unsigned int u = __float_as_uint(f);
  u += 0x7FFFu + ((u >> 16) & 1u);   // RNE (no NaN in this data)
  return (unsigned short)(u >> 16);
}
__device__ __forceinline__ float bf16u_to_f32(unsigned short h) {
  return __uint_as_float(((unsigned int)h) << 16);
}

// ---- prep: bf16 conversions + padded weight/feature layouts ----
// tmsg [M_TREE][128] bf16 ; whb [128][128] ; wob [128][192] ; wib [128][64]
// bfb  [NBOND][64] bf16: k<40 -> bond_feats[b][k], else 0
__global__ __launch_bounds__(256) void prep(const float* __restrict__ tm,
                                            const float* __restrict__ wh,
                                            const float* __restrict__ wo,
                                            const float* __restrict__ wi,
                                            const float* __restrict__ bf,
                                            unsigned short* __restrict__ tmsg,
                                            unsigned short* __restrict__ whb,
                                            unsigned short* __restrict__ wob,
                                            unsigned short* __restrict__ wib,
                                            unsigned short* __restrict__ bfb) {
  int i = blockIdx.x * 256 + threadIdx.x;
  const int n1 = M_TREE * H;          // 4,194,304
  const int n2 = H * H;               //    16,384
  const int n3 = H * KPAD;            //    24,576
  const int n4 = H * 64;              //     8,192
  const int n5 = NBOND * 64;          // 16,777,216
  if (i < n1) { tmsg[i] = f32_to_bf16(__builtin_nontemporal_load(tm + i)); return; }
  int j = i - n1;
  if (j < n2) { whb[j] = f32_to_bf16(wh[j]); return; }
  int k = j - n2;
  if (k < n3) {
    int g = k / KPAD, kk = k - g * KPAD;
    float v = 0.f;
    if (kk < 35)                   v = wo[g * FOUT + kk];
    else if (kk >= 36 && kk < 164) v = wo[g * FOUT + kk - 1];
    wob[k] = f32_to_bf16(v);
    return;
  }
  int m = k - n3;
  if (m < n4) {
    int g = m / 64, kk = m - g * 64;
    wib[m] = (kk < FBOND) ? f32_to_bf16(wi[g * FBOND + kk]) : (unsigned short)0;
    return;
  }
  int q = m - n4;
  if (q < n5) {
    int b = q >> 6, kk = q & 63;
    bfb[q] = (kk < FBOND) ? f32_to_bf16(__builtin_nontemporal_load(bf + b * FBOND + kk))
                          : (unsigned short)0;
  }
}

// ---- h0 = relu(bfb @ W_i^T), MFMA, dense bf16 table (round-1 gather source) ----
__global__ __launch_bounds__(256, 3) void wi_gemm(const unsigned short* __restrict__ bfb,
                                                  const unsigned short* __restrict__ wib,
                                                  unsigned short* __restrict__ h0) {
  __shared__ unsigned short sF[128][72];
  const int t = threadIdx.x;
  const int lane = t & 63;
  const int wave = t >> 6;
  const int n16 = lane & 15;
  const int quad = lane >> 4;
  const int b0 = blockIdx.x * 128;

  // stage 128 rows x 64 bf16 via 16B chunks (1024 chunks)
#pragma unroll
  for (int c = 0; c < 4; ++c) {
    int fl = c * 256 + t;
    int row = fl >> 3, q = fl & 7;
    *(u32x4*)&sF[row][q * 8] =
        *(const u32x4*)(bfb + (size_t)(b0 + row) * 64 + q * 8);
  }
  bf16x8 Bf[2][2];
#pragma unroll
  for (int kt = 0; kt < 2; ++kt)
#pragma unroll
    for (int nt = 0; nt < 2; ++nt)
      Bf[kt][nt] = *(const bf16x8*)(wib + ((wave * 2 + nt) * 16 + n16) * 64 + kt * 32 + quad * 8);
  __syncthreads();

  f32x4 acc[8][2];
  f32x4 zero = {0.f, 0.f, 0.f, 0.f};
#pragma unroll
  for (int mt = 0; mt < 8; ++mt) { acc[mt][0] = zero; acc[mt][1] = zero; }
#pragma unroll
  for (int kt = 0; kt < 2; ++kt)
#pragma unroll
    for (int mt = 0; mt < 8; ++mt) {
      bf16x8 av = *(const bf16x8*)&sF[mt * 16 + n16][kt * 32 + quad * 8];
      acc[mt][0] = __builtin_amdgcn_mfma_f32_16x16x32_bf16(av, Bf[kt][0], acc[mt][0], 0, 0, 0);
      acc[mt][1] = __builtin_amdgcn_mfma_f32_16x16x32_bf16(av, Bf[kt][1], acc[mt][1], 0, 0, 0);
    }
#pragma unroll
  for (int mt = 0; mt < 8; ++mt)
#pragma unroll
    for (int nt = 0; nt < 2; ++nt) {
      const int col = (wave * 2 + nt) * 16 + n16;
#pragma unroll
      for (int r = 0; r < 4; ++r) {
        const int b = b0 + mt * 16 + quad * 4 + r;
        h0[b * H + col] = f32_to_bf16(fmaxf(acc[mt][nt][r], 0.f));
      }
    }
}

// ---- one MP round: gout = relu(recompute_h0 + gather(msg)@W_h^T) ----
// h0 recomputed in-register (saves the 64 MB/round h0 stream)
__global__ __launch_bounds__(256, 5) void mp_step(const unsigned short* __restrict__ gin,
                                                  unsigned short* __restrict__ gout,
                                                  const unsigned short* __restrict__ tmsg,
                                                  const int* __restrict__ bond_graph,
                                                  const unsigned short* __restrict__ whb,
                                                  const unsigned short* __restrict__ wib,
                                                  const unsigned short* __restrict__ bfb) {
  __shared__ unsigned short snei[TB][136];   // 17408 B
  __shared__ unsigned short sBF[TB][72];     //  9216 B
  __shared__ int sBG[TB * MAXNB];            //  2560 B   total 29184 -> 5 blocks/CU
  const int t = threadIdx.x;
  const int lane = t & 63;
  const int wave = t >> 6;
  const int n16 = lane & 15;
  const int quad = lane >> 4;
  const int b0 = blockIdx.x * TB;

  for (int i = t; i < TB * MAXNB; i += 256) sBG[i] = bond_graph[b0 * MAXNB + i];
  // stage this block's bond feats (64 rows x 64 bf16, 512 16B-chunks)
#pragma unroll
  for (int c = 0; c < 2; ++c) {
    int fl = c * 256 + t;
    int row = fl >> 3, q = fl & 7;
    *(u32x4*)&sBF[row][q * 8] =
        *(const u32x4*)(bfb + (size_t)(b0 + row) * 64 + q * 8);
  }
  __syncthreads();

  const unsigned short* gsh = gin - (size_t)M_TREE * H;
  // gather: wave-uniform indices -> SALU addressing
  for (int lb = wave * 2; lb < TB; lb += 8) {
    unsigned int u[2][MAXNB];
#pragma unroll
    for (int p = 0; p < 2; ++p) {
      const int* ig = &sBG[(lb + p) * MAXNB];
#pragma unroll
      for (int j = 0; j < MAXNB; ++j) {
        int idx = __builtin_amdgcn_readfirstlane(ig[j]);
        const unsigned short* r = ((idx < M_TREE) ? tmsg : gsh) + (size_t)idx * H;
        u[p][j] = *(const unsigned int*)(r + 2 * lane);
      }
    }
#pragma unroll
    for (int p = 0; p < 2; ++p) {
      float a0 = 0.f, a1 = 0.f;
#pragma unroll
      for (int j = 0; j < MAXNB; ++j) {
        a0 += __uint_as_float(u[p][j] << 16);
        a1 += __uint_as_float(u[p][j] & 0xFFFF0000u);
      }
      unsigned int packed = ((unsigned int)f32_to_bf16(a1) << 16) | (unsigned int)f32_to_bf16(a0);
      *(unsigned int*)&snei[lb + p][2 * lane] = packed;
    }
  }

  // ---- recompute h0 fragments (same C/D layout as the W_h acc) ----
  f32x4 zero = {0.f, 0.f, 0.f, 0.f};
  unsigned int h0p[4][2][2];   // packed bf16 pairs {r0,r1},{r2,r3}
  {
    bf16x8 Bfi[2][2];
#pragma unroll
    for (int kt = 0; kt < 2; ++kt)
#pragma unroll
      for (int nt = 0; nt < 2; ++nt)
        Bfi[kt][nt] = *(const bf16x8*)(wib + ((wave * 2 + nt) * 16 + n16) * 64 + kt * 32 + quad * 8);
    f32x4 acci[4][2];
#pragma unroll
    for (int mt = 0; mt < 4; ++mt) { acci[mt][0] = zero; acci[mt][1] = zero; }
#pragma unroll
    for (int kt = 0; kt < 2; ++kt)
#pragma unroll
      for (int mt = 0; mt < 4; ++mt) {
        bf16x8 av = *(const bf16x8*)&sBF[mt * 16 + n16][kt * 32 + quad * 8];
        acci[mt][0] = __builtin_amdgcn_mfma_f32_16x16x32_bf16(av, Bfi[kt][0], acci[mt][0], 0, 0, 0);
        acci[mt][1] = __builtin_amdgcn_mfma_f32_16x16x32_bf16(av, Bfi[kt][1], acci[mt][1], 0, 0, 0);
      }
#pragma unroll
    for (int mt = 0; mt < 4; ++mt)
#pragma unroll
      for (int nt = 0; nt < 2; ++nt) {
        h0p[mt][nt][0] = (unsigned int)f32_to_bf16(fmaxf(acci[mt][nt][0], 0.f)) |
                         ((unsigned int)f32_to_bf16(fmaxf(acci[mt][nt][1], 0.f)) << 16);
        h0p[mt][nt][1] = (unsigned int)f32_to_bf16(fmaxf(acci[mt][nt][2], 0.f)) |
                         ((unsigned int)f32_to_bf16(fmaxf(acci[mt][nt][3], 0.f)) << 16);
      }
  }

  bf16x8 Bf[4][2];
#pragma unroll
  for (int kt = 0; kt < 4; ++kt)
#pragma unroll
    for (int nt = 0; nt < 2; ++nt)
      Bf[kt][nt] = *(const bf16x8*)(whb + ((wave * 2 + nt) * 16 + n16) * H + kt * 32 + quad * 8);
  __syncthreads();   // gather LDS writes complete

  f32x4 acc[4][2];
#pragma unroll
  for (int mt = 0; mt < 4; ++mt) { acc[mt][0] = zero; acc[mt][1] = zero; }
#pragma unroll
  for (int kt = 0; kt < 4; ++kt)
#pragma unroll
    for (int mt = 0; mt < 4; ++mt) {
      bf16x8 av = *(const bf16x8*)&snei[mt * 16 + n16][kt * 32 + quad * 8];
      acc[mt][0] = __builtin_amdgcn_mfma_f32_16x16x32_bf16(av, Bf[kt][0], acc[mt][0], 0, 0, 0);
      acc[mt][1] = __builtin_amdgcn_mfma_f32_16x16x32_bf16(av, Bf[kt][1], acc[mt][1], 0, 0, 0);
    }
  __syncthreads();   // snei reads done

  // final = relu(h0 + acc) in-register, stage -> snei
#pragma unroll
  for (int mt = 0; mt < 4; ++mt)
#pragma unroll
    for (int nt = 0; nt < 2; ++nt) {
      const int col = (wave * 2 + nt) * 16 + n16;
#pragma unroll
      for (int r = 0; r < 4; ++r) {
        unsigned int hp = h0p[mt][nt][r >> 1];
        float hv = bf16u_to_f32((unsigned short)((r & 1) ? (hp >> 16) : hp));
        snei[mt * 16 + quad * 4 + r][col] = f32_to_bf16(fmaxf(hv + acc[mt][nt][r], 0.f));
      }
    }
  __syncthreads();

  // vectorized store: 64 rows x 16 chunks = 1024 -> 4/thread
  const size_t gbase = (size_t)b0 * H;
#pragma unroll
  for (int c = 0; c < 4; ++c) {
    int fl = c * 256 + t;
    int row = fl >> 4;
    int col = (fl & 15) * 8;
    *(u32x4*)(gout + gbase + (size_t)row * H + col) = *(const u32x4*)&snei[row][col];
  }
}

// ---- readout: 64 atoms (2 mols)/block, MFMA over K=192, 4 blocks/CU ----
__global__ __launch_bounds__(256, 4) void readout(const float* __restrict__ atom_feats,
                                                  const unsigned short* __restrict__ gm,
                                                  const unsigned short* __restrict__ tmsg,
                                                  const int* __restrict__ atom_graph,
                                                  const unsigned short* __restrict__ wob,
                                                  const float* __restrict__ b_o,
                                                  float* __restrict__ out) {
  __shared__ unsigned short sA[TA][200];
  __shared__ int sAG[TA * MAXNB];
  const int t = threadIdx.x;
  const int lane = t & 63;
  const int wave = t >> 6;
  const int n16 = lane & 15;
  const int quad = lane >> 4;
  const int blk = blockIdx.x;
  const int abase = blk * TA;

  for (int i = t; i < TA * MAXNB; i += 256)
    sAG[i] = __builtin_nontemporal_load(atom_graph + abase * MAXNB + i);
  for (int i = t; i < TA * FATOM; i += 256) {
    int a = i / FATOM, f = i - a * FATOM;
    sA[a][f] = f32_to_bf16(__builtin_nontemporal_load(atom_feats + abase * FATOM + i));
  }
  if (t < TA) sA[t][35] = 0;
  for (int i = t; i < TA * 28; i += 256) {
    int a = i / 28, c = 164 + i - a * 28;
    sA[a][c] = 0;
  }
  __syncthreads();

  const unsigned short* gsh = gm - (size_t)M_TREE * H;
  for (int la = wave * 2; la < TA; la += 8) {
    unsigned int u[2][MAXNB];
#pragma unroll
    for (int p = 0; p < 2; ++p) {
      const int* ig = &sAG[(la + p) * MAXNB];
#pragma unroll
      for (int j = 0; j < MAXNB; ++j) {
        int idx = __builtin_amdgcn_readfirstlane(ig[j]);
        const unsigned short* r = ((idx < M_TREE) ? tmsg : gsh) + (size_t)idx * H;
        u[p][j] = *(const unsigned int*)(r + 2 * lane);
      }
    }
#pragma unroll
    for (int p = 0; p < 2; ++p) {
      float a0 = 0.f, a1 = 0.f;
#pragma unroll
      for (int j = 0; j < MAXNB; ++j) {
        a0 += __uint_as_float(u[p][j] << 16);
        a1 += __uint_as_float(u[p][j] & 0xFFFF0000u);
      }
      unsigned int packed = ((unsigned int)f32_to_bf16(a1) << 16) | (unsigned int)f32_to_bf16(a0);
      *(unsigned int*)&sA[la + p][36 + 2 * lane] = packed;
    }
  }

  bf16x8 Bf[6][2];
#pragma unroll
  for (int kt = 0; kt < 6; ++kt)
#pragma unroll
    for (int nt = 0; nt < 2; ++nt)
      Bf[kt][nt] = *(const bf16x8*)(wob + ((wave * 2 + nt) * 16 + n16) * KPAD + kt * 32 + quad * 8);
  __syncthreads();

  f32x4 acc[4][2];
  f32x4 zero = {0.f, 0.f, 0.f, 0.f};
#pragma unroll
  for (int mt = 0; mt < 4; ++mt) { acc[mt][0] = zero; acc[mt][1] = zero; }
#pragma unroll
  for (int kt = 0; kt < 6; ++kt)
#pragma unroll
    for (int mt = 0; mt < 4; ++mt) {
      bf16x8 av = *(const bf16x8*)&sA[mt * 16 + n16][kt * 32 + quad * 8];
      acc[mt][0] = __builtin_amdgcn_mfma_f32_16x16x32_bf16(av, Bf[kt][0], acc[mt][0], 0, 0, 0);
      acc[mt][1] = __builtin_amdgcn_mfma_f32_16x16x32_bf16(av, Bf[kt][1], acc[mt][1], 0, 0, 0);
    }

  float bo[2] = { b_o[(wave * 2) * 16 + n16], b_o[(wave * 2 + 1) * 16 + n16] };
  float part[2][2] = {{0.f,0.f},{0.f,0.f}};
#pragma unroll
  for (int mt = 0; mt < 4; ++mt)
#pragma unroll
    for (int nt = 0; nt < 2; ++nt)
#pragma unroll
      for (int r = 0; r < 4; ++r)
        part[mt >> 1][nt] += fmaxf(acc[mt][nt][r] + bo[nt], 0.f);
#pragma unroll
  for (int mol = 0; mol < 2; ++mol)
#pragma unroll
    for (int nt = 0; nt < 2; ++nt) {
      float p = part[mol][nt];
      p += __shfl_xor(p, 16);
      p += __shfl_xor(p, 32);
      if (lane < 16)
        out[(blk * 2 + mol) * H + (wave * 2 + nt) * 16 + lane] = p * (1.0f / APM);
    }
}

extern "C" void kernel_launch(void* const* d_in, const int* in_sizes, int n_in,
                              void* d_out, int out_size, void* d_ws, size_t ws_size,
                              hipStream_t stream) {
  (void)in_sizes; (void)n_in; (void)out_size; (void)ws_size;
  const float* atom_feats   = (const float*)d_in[0];
  const float* bond_feats   = (const float*)d_in[1];
  const float* tree_message = (const float*)d_in[2];
  const int*   atom_graph   = (const int*)d_in[3];
  const int*   bond_graph   = (const int*)d_in[4];
  const float* W_i = (const float*)d_in[6];
  const float* W_h = (const float*)d_in[7];
  const float* W_o = (const float*)d_in[8];
  const float* b_o = (const float*)d_in[9];
  float* out = (float*)d_out;

  char* ws = (char*)d_ws;
  unsigned short* tmsg = (unsigned short*)(ws);                    //  8,388,608 B
  unsigned short* whb  = (unsigned short*)(ws + 8388608);          //     32,768 B
  unsigned short* wob  = (unsigned short*)(ws + 8421376);          //     49,152 B
  unsigned short* wib  = (unsigned short*)(ws + 8470528);          //     16,384 B
  unsigned short* bfb  = (unsigned short*)(ws + 8486912);          // 33,554,432 B
  unsigned short* h0   = (unsigned short*)(ws + 42041344);         // 67,108,864 B
  unsigned short* gm0  = (unsigned short*)(ws + 109150208);        // 67,108,864 B
  unsigned short* gm1  = (unsigned short*)(ws + 176259072);        // 67,108,864 B
  // total: 243,367,936 B

  prep<<<82112, 256, 0, stream>>>(tree_message, W_h, W_o, W_i, bond_feats,
                                  tmsg, whb, wob, wib, bfb);
  wi_gemm<<<NBOND / 128, 256, 0, stream>>>(bfb, wib, h0);
  mp_step<<<NBOND / TB, 256, 0, stream>>>(h0,  gm0, tmsg, bond_graph, whb, wib, bfb);
  mp_step<<<NBOND / TB, 256, 0, stream>>>(gm0, gm1, tmsg, bond_graph, whb, wib, bfb);
  mp_step<<<NBOND / TB, 256, 0, stream>>>(gm1, gm0, tmsg, bond_graph, whb, wib, bfb);
  mp_step<<<NBOND / TB, 256, 0, stream>>>(gm0, gm1, tmsg, bond_graph, whb, wib, bfb);
  mp_step<<<NBOND / TB, 256, 0, stream>>>(gm1, gm0, tmsg, bond_graph, whb, wib, bfb);
  readout<<<NATOM / TA, 256, 0, stream>>>(atom_feats, gm0, tmsg, atom_graph, wob, b_o, out);
}

// Round 10
// 771.072 us; speedup vs baseline: 2.9530x; 1.0633x over previous
//
#include <hip/hip_runtime.h>

// ---- problem constants ----
#define H       128
#define MAXNB   10
#define M_TREE  32768
#define NBOND   262144
#define NATOM   131072
#define FATOM   35
#define FBOND   40
#define FOUT    163
#define KPAD    192
#define NMOLS   4096
#define APM     32
#define TB      64      // bonds per block in mp_step
#define TA      64      // atoms per block in readout

typedef __bf16 bf16x8 __attribute__((ext_vector_type(8)));
typedef float  f32x4  __attribute__((ext_vector_type(4)));
typedef unsigned int u32x4 __attribute__((ext_vector_type(4)));
typedef unsigned int u32x2 __attribute__((ext_vector_type(2)));

__device__ __forceinline__ unsigned short f32_to_bf16(float f) {
  unsigned int u = __float_as_uint(f);
  u += 0x7FFFu + ((u >> 16) & 1u);   // RNE (no NaN in this data)
  return (unsigned short)(u >> 16);
}
__device__ __forceinline__ float bf16u_to_f32(unsigned short h) {
  return __uint_as_float(((unsigned int)h) << 16);
}
// packed pair: relu(bf16(a) + bf16(h)) -> packed bf16
__device__ __forceinline__ unsigned int bfpair_addrelu(unsigned int a, unsigned int h) {
  float a0 = __uint_as_float(a << 16), a1 = __uint_as_float(a & 0xFFFF0000u);
  float h0v = __uint_as_float(h << 16), h1v = __uint_as_float(h & 0xFFFF0000u);
  float r0 = fmaxf(a0 + h0v, 0.f), r1 = fmaxf(a1 + h1v, 0.f);
  return ((unsigned int)f32_to_bf16(r1) << 16) | (unsigned int)f32_to_bf16(r0);
}

// ---- prep: bf16 conversions + padded weight layouts ----
// blocks [0,4096): tmsg vectorized (4 f32/thread). blocks [4096,4288): weights scalar.
__global__ __launch_bounds__(256) void prep(const float* __restrict__ tm,
                                            const float* __restrict__ wh,
                                            const float* __restrict__ wo,
                                            const float* __restrict__ wi,
                                            unsigned short* __restrict__ tmsg,
                                            unsigned short* __restrict__ whb,
                                            unsigned short* __restrict__ wob,
                                            unsigned short* __restrict__ wib) {
  const int blk = blockIdx.x;
  if (blk < 4096) {
    int i = (blk * 256 + threadIdx.x) * 4;      // < 4,194,304
    f32x4 v = __builtin_nontemporal_load((const f32x4*)(tm + i));
    u32x2 p;
    p.x = (unsigned int)f32_to_bf16(v.x) | ((unsigned int)f32_to_bf16(v.y) << 16);
    p.y = (unsigned int)f32_to_bf16(v.z) | ((unsigned int)f32_to_bf16(v.w) << 16);
    *(u32x2*)(tmsg + i) = p;
    return;
  }
  int j = (blk - 4096) * 256 + threadIdx.x;
  const int n2 = H * H;                 // 16,384
  const int n3 = H * KPAD;              // 24,576
  const int n4 = H * 64;                //  8,192
  if (j < n2) { whb[j] = f32_to_bf16(wh[j]); return; }
  int k = j - n2;
  if (k < n3) {
    int g = k / KPAD, kk = k - g * KPAD;
    float v = 0.f;
    if (kk < 35)                   v = wo[g * FOUT + kk];
    else if (kk >= 36 && kk < 164) v = wo[g * FOUT + kk - 1];
    wob[k] = f32_to_bf16(v);
    return;
  }
  int m = k - n3;
  if (m < n4) {
    int g = m / 64, kk = m - g * 64;
    wib[m] = (kk < FBOND) ? f32_to_bf16(wi[g * FBOND + kk]) : (unsigned short)0;
  }
}

// ---- h0 = relu(bond_feats @ W_i^T), MFMA, stored bf16 ----
__global__ __launch_bounds__(256, 3) void wi_gemm(const float* __restrict__ bond_feats,
                                                  const unsigned short* __restrict__ wib,
                                                  unsigned short* __restrict__ h0) {
  __shared__ unsigned short sF[128][72];
  const int t = threadIdx.x;
  const int lane = t & 63;
  const int wave = t >> 6;
  const int n16 = lane & 15;
  const int quad = lane >> 4;
  const int b0 = blockIdx.x * 128;

  // flat float4 staging: 128 rows x 40 f32 = 1280 float4 (40 % 4 == 0: no row straddle)
#pragma unroll
  for (int c = 0; c < 5; ++c) {
    int q = c * 256 + t;
    f32x4 v = __builtin_nontemporal_load((const f32x4*)(bond_feats + (size_t)b0 * FBOND + q * 4));
    int flat = q * 4;
    int row = flat / 40, col = flat - row * 40;
    u32x2 p;
    p.x = (unsigned int)f32_to_bf16(v.x) | ((unsigned int)f32_to_bf16(v.y) << 16);
    p.y = (unsigned int)f32_to_bf16(v.z) | ((unsigned int)f32_to_bf16(v.w) << 16);
    *(u32x2*)&sF[row][col] = p;
  }
  for (int i = t; i < 128 * 24; i += 256) {    // zero cols 40..63
    int b = i / 24, c = 40 + i - b * 24;
    sF[b][c] = 0;
  }
  bf16x8 Bf[2][2];
#pragma unroll
  for (int kt = 0; kt < 2; ++kt)
#pragma unroll
    for (int nt = 0; nt < 2; ++nt)
      Bf[kt][nt] = *(const bf16x8*)(wib + ((wave * 2 + nt) * 16 + n16) * 64 + kt * 32 + quad * 8);
  __syncthreads();

  f32x4 acc[8][2];
  f32x4 zero = {0.f, 0.f, 0.f, 0.f};
#pragma unroll
  for (int mt = 0; mt < 8; ++mt) { acc[mt][0] = zero; acc[mt][1] = zero; }
#pragma unroll
  for (int kt = 0; kt < 2; ++kt)
#pragma unroll
    for (int mt = 0; mt < 8; ++mt) {
      bf16x8 av = *(const bf16x8*)&sF[mt * 16 + n16][kt * 32 + quad * 8];
      acc[mt][0] = __builtin_amdgcn_mfma_f32_16x16x32_bf16(av, Bf[kt][0], acc[mt][0], 0, 0, 0);
      acc[mt][1] = __builtin_amdgcn_mfma_f32_16x16x32_bf16(av, Bf[kt][1], acc[mt][1], 0, 0, 0);
    }
#pragma unroll
  for (int mt = 0; mt < 8; ++mt)
#pragma unroll
    for (int nt = 0; nt < 2; ++nt) {
      const int col = (wave * 2 + nt) * 16 + n16;
#pragma unroll
      for (int r = 0; r < 4; ++r) {
        const int b = b0 + mt * 16 + quad * 4 + r;
        h0[b * H + col] = f32_to_bf16(fmaxf(acc[mt][nt][r], 0.f));
      }
    }
}

// ---- one MP round: gm_out = relu(h0 + gather(msg)@W_h^T) ----
// TB=64: LDS 19968 B, VGPR<=64 -> 8 blocks/CU (100% occupancy)
__global__ __launch_bounds__(256, 8) void mp_step(const unsigned short* __restrict__ gm_in,
                                                  unsigned short* __restrict__ gm_out,
                                                  const unsigned short* __restrict__ h0,
                                                  const unsigned short* __restrict__ tmsg,
                                                  const int* __restrict__ bond_graph,
                                                  const unsigned short* __restrict__ whb) {
  __shared__ unsigned short snei[TB][136];   // 17408 B
  __shared__ int sBG[TB * MAXNB];            //  2560 B
  const int t = threadIdx.x;
  const int lane = t & 63;
  const int wave = t >> 6;
  const int n16 = lane & 15;
  const int quad = lane >> 4;
  const int b0 = blockIdx.x * TB;

  for (int i = t; i < TB * MAXNB; i += 256) sBG[i] = bond_graph[b0 * MAXNB + i];
  __syncthreads();

  const unsigned short* gsh = gm_in - (size_t)M_TREE * H;
  // gather: wave-uniform indices -> SALU addressing; 4 bonds/iter = 40 loads in flight
  for (int lb = wave * 4; lb < TB; lb += 16) {
    unsigned int u[4][MAXNB];
#pragma unroll
    for (int p = 0; p < 4; ++p) {
      const int* ig = &sBG[(lb + p) * MAXNB];
#pragma unroll
      for (int j = 0; j < MAXNB; ++j) {
        int idx = __builtin_amdgcn_readfirstlane(ig[j]);
        const unsigned short* r = ((idx < M_TREE) ? tmsg : gsh) + (size_t)idx * H;
        u[p][j] = *(const unsigned int*)(r + 2 * lane);
      }
    }
#pragma unroll
    for (int p = 0; p < 4; ++p) {
      float a0 = 0.f, a1 = 0.f;
#pragma unroll
      for (int j = 0; j < MAXNB; ++j) {
        a0 += __uint_as_float(u[p][j] << 16);
        a1 += __uint_as_float(u[p][j] & 0xFFFF0000u);
      }
      unsigned int packed = ((unsigned int)f32_to_bf16(a1) << 16) | (unsigned int)f32_to_bf16(a0);
      *(unsigned int*)&snei[lb + p][2 * lane] = packed;
    }
  }

  // W_h^T fragments (after gather to limit register overlap): 32 VGPRs
  bf16x8 Bf[4][2];
#pragma unroll
  for (int kt = 0; kt < 4; ++kt)
#pragma unroll
    for (int nt = 0; nt < 2; ++nt)
      Bf[kt][nt] = *(const bf16x8*)(whb + ((wave * 2 + nt) * 16 + n16) * H + kt * 32 + quad * 8);
  __syncthreads();

  f32x4 acc[4][2];
  f32x4 zero = {0.f, 0.f, 0.f, 0.f};
#pragma unroll
  for (int mt = 0; mt < 4; ++mt) { acc[mt][0] = zero; acc[mt][1] = zero; }
#pragma unroll
  for (int kt = 0; kt < 4; ++kt)
#pragma unroll
    for (int mt = 0; mt < 4; ++mt) {
      bf16x8 av = *(const bf16x8*)&snei[mt * 16 + n16][kt * 32 + quad * 8];
      acc[mt][0] = __builtin_amdgcn_mfma_f32_16x16x32_bf16(av, Bf[kt][0], acc[mt][0], 0, 0, 0);
      acc[mt][1] = __builtin_amdgcn_mfma_f32_16x16x32_bf16(av, Bf[kt][1], acc[mt][1], 0, 0, 0);
    }
  __syncthreads();   // all MFMA reads of snei done

  // stage acc -> snei as bf16
#pragma unroll
  for (int mt = 0; mt < 4; ++mt)
#pragma unroll
    for (int nt = 0; nt < 2; ++nt) {
      const int col = (wave * 2 + nt) * 16 + n16;
#pragma unroll
      for (int r = 0; r < 4; ++r)
        snei[mt * 16 + quad * 4 + r][col] = f32_to_bf16(acc[mt][nt][r]);
    }
  __syncthreads();

  // vectorized epilogue: 64 rows x 16 chunks = 1024 -> 4/thread
  const size_t gbase = (size_t)b0 * H;
#pragma unroll
  for (int c = 0; c < 4; ++c) {
    int fl = c * 256 + t;
    int row = fl >> 4;
    int col = (fl & 15) * 8;
    u32x4 a4 = *(const u32x4*)&snei[row][col];
    u32x4 h4 = *(const u32x4*)(h0 + gbase + (size_t)row * H + col);
    u32x4 o4;
    o4.x = bfpair_addrelu(a4.x, h4.x);
    o4.y = bfpair_addrelu(a4.y, h4.y);
    o4.z = bfpair_addrelu(a4.z, h4.z);
    o4.w = bfpair_addrelu(a4.w, h4.w);
    *(u32x4*)(gm_out + gbase + (size_t)row * H + col) = o4;
  }
}

// ---- readout: 64 atoms (2 mols)/block, MFMA over K=192, 5 blocks/CU ----
__global__ __launch_bounds__(256, 5) void readout(const float* __restrict__ atom_feats,
                                                  const unsigned short* __restrict__ gm,
                                                  const unsigned short* __restrict__ tmsg,
                                                  const int* __restrict__ atom_graph,
                                                  const unsigned short* __restrict__ wob,
                                                  const float* __restrict__ b_o,
                                                  float* __restrict__ out) {
  __shared__ unsigned short sA[TA][200];     // 25600 B
  __shared__ int sAG[TA * MAXNB];            //  2560 B
  const int t = threadIdx.x;
  const int lane = t & 63;
  const int wave = t >> 6;
  const int n16 = lane & 15;
  const int quad = lane >> 4;
  const int blk = blockIdx.x;
  const int abase = blk * TA;

  for (int i = t; i < TA * MAXNB; i += 256)
    sAG[i] = __builtin_nontemporal_load(atom_graph + abase * MAXNB + i);
  for (int i = t; i < TA * FATOM; i += 256) {
    int a = i / FATOM, f = i - a * FATOM;
    sA[a][f] = f32_to_bf16(__builtin_nontemporal_load(atom_feats + abase * FATOM + i));
  }
  if (t < TA) sA[t][35] = 0;
  for (int i = t; i < TA * 28; i += 256) {
    int a = i / 28, c = 164 + i - a * 28;
    sA[a][c] = 0;
  }
  __syncthreads();

  const unsigned short* gsh = gm - (size_t)M_TREE * H;
  for (int la = wave * 2; la < TA; la += 8) {
    unsigned int u[2][MAXNB];
#pragma unroll
    for (int p = 0; p < 2; ++p) {
      const int* ig = &sAG[(la + p) * MAXNB];
#pragma unroll
      for (int j = 0; j < MAXNB; ++j) {
        int idx = __builtin_amdgcn_readfirstlane(ig[j]);
        const unsigned short* r = ((idx < M_TREE) ? tmsg : gsh) + (size_t)idx * H;
        u[p][j] = *(const unsigned int*)(r + 2 * lane);
      }
    }
#pragma unroll
    for (int p = 0; p < 2; ++p) {
      float a0 = 0.f, a1 = 0.f;
#pragma unroll
      for (int j = 0; j < MAXNB; ++j) {
        a0 += __uint_as_float(u[p][j] << 16);
        a1 += __uint_as_float(u[p][j] & 0xFFFF0000u);
      }
      unsigned int packed = ((unsigned int)f32_to_bf16(a1) << 16) | (unsigned int)f32_to_bf16(a0);
      *(unsigned int*)&sA[la + p][36 + 2 * lane] = packed;
    }
  }

  bf16x8 Bf[6][2];
#pragma unroll
  for (int kt = 0; kt < 6; ++kt)
#pragma unroll
    for (int nt = 0; nt < 2; ++nt)
      Bf[kt][nt] = *(const bf16x8*)(wob + ((wave * 2 + nt) * 16 + n16) * KPAD + kt * 32 + quad * 8);
  __syncthreads();

  f32x4 acc[4][2];
  f32x4 zero = {0.f, 0.f, 0.f, 0.f};
#pragma unroll
  for (int mt = 0; mt < 4; ++mt) { acc[mt][0] = zero; acc[mt][1] = zero; }
#pragma unroll
  for (int kt = 0; kt < 6; ++kt)
#pragma unroll
    for (int mt = 0; mt < 4; ++mt) {
      bf16x8 av = *(const bf16x8*)&sA[mt * 16 + n16][kt * 32 + quad * 8];
      acc[mt][0] = __builtin_amdgcn_mfma_f32_16x16x32_bf16(av, Bf[kt][0], acc[mt][0], 0, 0, 0);
      acc[mt][1] = __builtin_amdgcn_mfma_f32_16x16x32_bf16(av, Bf[kt][1], acc[mt][1], 0, 0, 0);
    }

  float bo[2] = { b_o[(wave * 2) * 16 + n16], b_o[(wave * 2 + 1) * 16 + n16] };
  float part[2][2] = {{0.f,0.f},{0.f,0.f}};
#pragma unroll
  for (int mt = 0; mt < 4; ++mt)
#pragma unroll
    for (int nt = 0; nt < 2; ++nt)
#pragma unroll
      for (int r = 0; r < 4; ++r)
        part[mt >> 1][nt] += fmaxf(acc[mt][nt][r] + bo[nt], 0.f);
#pragma unroll
  for (int mol = 0; mol < 2; ++mol)
#pragma unroll
    for (int nt = 0; nt < 2; ++nt) {
      float p = part[mol][nt];
      p += __shfl_xor(p, 16);
      p += __shfl_xor(p, 32);
      if (lane < 16)
        out[(blk * 2 + mol) * H + (wave * 2 + nt) * 16 + lane] = p * (1.0f / APM);
    }
}

extern "C" void kernel_launch(void* const* d_in, const int* in_sizes, int n_in,
                              void* d_out, int out_size, void* d_ws, size_t ws_size,
                              hipStream_t stream) {
  (void)in_sizes; (void)n_in; (void)out_size; (void)ws_size;
  const float* atom_feats   = (const float*)d_in[0];
  const float* bond_feats   = (const float*)d_in[1];
  const float* tree_message = (const float*)d_in[2];
  const int*   atom_graph   = (const int*)d_in[3];
  const int*   bond_graph   = (const int*)d_in[4];
  const float* W_i = (const float*)d_in[6];
  const float* W_h = (const float*)d_in[7];
  const float* W_o = (const float*)d_in[8];
  const float* b_o = (const float*)d_in[9];
  float* out = (float*)d_out;

  char* ws = (char*)d_ws;
  unsigned short* tmsg = (unsigned short*)(ws);                    //  8,388,608 B
  unsigned short* whb  = (unsigned short*)(ws + 8388608);
  unsigned short* wob  = (unsigned short*)(ws + 8421376);
  unsigned short* wib  = (unsigned short*)(ws + 8470528);
  unsigned short* h0   = (unsigned short*)(ws + 8486912);          // 67,108,864 B
  unsigned short* gm0  = (unsigned short*)(ws + 75595776);
  unsigned short* gm1  = (unsigned short*)(ws + 142704640);

  prep<<<4288, 256, 0, stream>>>(tree_message, W_h, W_o, W_i, tmsg, whb, wob, wib);
  wi_gemm<<<NBOND / 128, 256, 0, stream>>>(bond_feats, wib, h0);
  mp_step<<<NBOND / TB, 256, 0, stream>>>(h0,  gm0, h0, tmsg, bond_graph, whb);
  mp_step<<<NBOND / TB, 256, 0, stream>>>(gm0, gm1, h0, tmsg, bond_graph, whb);
  mp_step<<<NBOND / TB, 256, 0, stream>>>(gm1, gm0, h0, tmsg, bond_graph, whb);
  mp_step<<<NBOND / TB, 256, 0, stream>>>(gm0, gm1, h0, tmsg, bond_graph, whb);
  mp_step<<<NBOND / TB, 256, 0, stream>>>(gm1, gm0, h0, tmsg, bond_graph, whb);
  readout<<<NATOM / TA, 256, 0, stream>>>(atom_feats, gm0, tmsg, atom_graph, wob, b_o, out);
}

// Round 11
// 748.677 us; speedup vs baseline: 3.0414x; 1.0299x over previous
//
#include <hip/hip_runtime.h>

// ---- problem constants ----
#define H       128
#define MAXNB   10
#define M_TREE  32768
#define NBOND   262144
#define NATOM   131072
#define FATOM   35
#define FBOND   40
#define FOUT    163
#define KPAD    192
#define NMOLS   4096
#define APM     32
#define TB      64      // bonds per block in mp_step
#define TA      64      // atoms per block in readout

typedef __bf16 bf16x8 __attribute__((ext_vector_type(8)));
typedef float  f32x4  __attribute__((ext_vector_type(4)));
typedef unsigned int u32x4 __attribute__((ext_vector_type(4)));
typedef unsigned int u32x2 __attribute__((ext_vector_type(2)));

__device__ __forceinline__ unsigned short f32_to_bf16(float f) {
  unsigned int u = __float_as_uint(f);
  u += 0x7FFFu + ((u >> 16) & 1u);   // RNE (no NaN in this data)
  return (unsigned short)(u >> 16);
}
__device__ __forceinline__ float bf16u_to_f32(unsigned short h) {
  return __uint_as_float(((unsigned int)h) << 16);
}
// packed pair: relu(bf16(a) + bf16(h)) -> packed bf16
__device__ __forceinline__ unsigned int bfpair_addrelu(unsigned int a, unsigned int h) {
  float a0 = __uint_as_float(a << 16), a1 = __uint_as_float(a & 0xFFFF0000u);
  float h0v = __uint_as_float(h << 16), h1v = __uint_as_float(h & 0xFFFF0000u);
  float r0 = fmaxf(a0 + h0v, 0.f), r1 = fmaxf(a1 + h1v, 0.f);
  return ((unsigned int)f32_to_bf16(r1) << 16) | (unsigned int)f32_to_bf16(r0);
}

// ---- prep: bf16 conversions + padded weight layouts ----
// blocks [0,4096): tmsg vectorized (4 f32/thread). blocks [4096,4288): weights scalar.
__global__ __launch_bounds__(256) void prep(const float* __restrict__ tm,
                                            const float* __restrict__ wh,
                                            const float* __restrict__ wo,
                                            const float* __restrict__ wi,
                                            unsigned short* __restrict__ tmsg,
                                            unsigned short* __restrict__ whb,
                                            unsigned short* __restrict__ wob,
                                            unsigned short* __restrict__ wib) {
  const int blk = blockIdx.x;
  if (blk < 4096) {
    int i = (blk * 256 + threadIdx.x) * 4;      // < 4,194,304
    f32x4 v = __builtin_nontemporal_load((const f32x4*)(tm + i));
    u32x2 p;
    p.x = (unsigned int)f32_to_bf16(v.x) | ((unsigned int)f32_to_bf16(v.y) << 16);
    p.y = (unsigned int)f32_to_bf16(v.z) | ((unsigned int)f32_to_bf16(v.w) << 16);
    *(u32x2*)(tmsg + i) = p;
    return;
  }
  int j = (blk - 4096) * 256 + threadIdx.x;
  const int n2 = H * H;                 // 16,384
  const int n3 = H * KPAD;              // 24,576
  const int n4 = H * 64;                //  8,192
  if (j < n2) { whb[j] = f32_to_bf16(wh[j]); return; }
  int k = j - n2;
  if (k < n3) {
    int g = k / KPAD, kk = k - g * KPAD;
    float v = 0.f;
    if (kk < 35)                   v = wo[g * FOUT + kk];
    else if (kk >= 36 && kk < 164) v = wo[g * FOUT + kk - 1];
    wob[k] = f32_to_bf16(v);
    return;
  }
  int m = k - n3;
  if (m < n4) {
    int g = m / 64, kk = m - g * 64;
    wib[m] = (kk < FBOND) ? f32_to_bf16(wi[g * FBOND + kk]) : (unsigned short)0;
  }
}

// ---- h0 = relu(bond_feats @ W_i^T), MFMA, stored bf16 ----
__global__ __launch_bounds__(256, 3) void wi_gemm(const float* __restrict__ bond_feats,
                                                  const unsigned short* __restrict__ wib,
                                                  unsigned short* __restrict__ h0) {
  __shared__ unsigned short sF[128][72];
  const int t = threadIdx.x;
  const int lane = t & 63;
  const int wave = t >> 6;
  const int n16 = lane & 15;
  const int quad = lane >> 4;
  const int b0 = blockIdx.x * 128;

  // flat float4 staging: 128 rows x 40 f32 = 1280 float4 (40 % 4 == 0: no row straddle)
#pragma unroll
  for (int c = 0; c < 5; ++c) {
    int q = c * 256 + t;
    f32x4 v = __builtin_nontemporal_load((const f32x4*)(bond_feats + (size_t)b0 * FBOND + q * 4));
    int flat = q * 4;
    int row = flat / 40, col = flat - row * 40;
    u32x2 p;
    p.x = (unsigned int)f32_to_bf16(v.x) | ((unsigned int)f32_to_bf16(v.y) << 16);
    p.y = (unsigned int)f32_to_bf16(v.z) | ((unsigned int)f32_to_bf16(v.w) << 16);
    *(u32x2*)&sF[row][col] = p;
  }
  for (int i = t; i < 128 * 24; i += 256) {    // zero cols 40..63
    int b = i / 24, c = 40 + i - b * 24;
    sF[b][c] = 0;
  }
  bf16x8 Bf[2][2];
#pragma unroll
  for (int kt = 0; kt < 2; ++kt)
#pragma unroll
    for (int nt = 0; nt < 2; ++nt)
      Bf[kt][nt] = *(const bf16x8*)(wib + ((wave * 2 + nt) * 16 + n16) * 64 + kt * 32 + quad * 8);
  __syncthreads();

  f32x4 acc[8][2];
  f32x4 zero = {0.f, 0.f, 0.f, 0.f};
#pragma unroll
  for (int mt = 0; mt < 8; ++mt) { acc[mt][0] = zero; acc[mt][1] = zero; }
#pragma unroll
  for (int kt = 0; kt < 2; ++kt)
#pragma unroll
    for (int mt = 0; mt < 8; ++mt) {
      bf16x8 av = *(const bf16x8*)&sF[mt * 16 + n16][kt * 32 + quad * 8];
      acc[mt][0] = __builtin_amdgcn_mfma_f32_16x16x32_bf16(av, Bf[kt][0], acc[mt][0], 0, 0, 0);
      acc[mt][1] = __builtin_amdgcn_mfma_f32_16x16x32_bf16(av, Bf[kt][1], acc[mt][1], 0, 0, 0);
    }
#pragma unroll
  for (int mt = 0; mt < 8; ++mt)
#pragma unroll
    for (int nt = 0; nt < 2; ++nt) {
      const int col = (wave * 2 + nt) * 16 + n16;
#pragma unroll
      for (int r = 0; r < 4; ++r) {
        const int b = b0 + mt * 16 + quad * 4 + r;
        h0[b * H + col] = f32_to_bf16(fmaxf(acc[mt][nt][r], 0.f));
      }
    }
}

// ---- one MP round: gm_out = relu(h0 + gather(msg)@W_h^T) ----
// TB=64, 6 blocks/CU (empirically best: 8/CU raises L2 churn, FETCH+WRITE up, dur up)
__global__ __launch_bounds__(256, 6) void mp_step(const unsigned short* __restrict__ gm_in,
                                                  unsigned short* __restrict__ gm_out,
                                                  const unsigned short* __restrict__ h0,
                                                  const unsigned short* __restrict__ tmsg,
                                                  const int* __restrict__ bond_graph,
                                                  const unsigned short* __restrict__ whb) {
  __shared__ unsigned short snei[TB][136];   // 17408 B
  __shared__ int sBG[TB * MAXNB];            //  2560 B
  const int t = threadIdx.x;
  const int lane = t & 63;
  const int wave = t >> 6;
  const int n16 = lane & 15;
  const int quad = lane >> 4;
  const int b0 = blockIdx.x * TB;

  for (int i = t; i < TB * MAXNB; i += 256) sBG[i] = bond_graph[b0 * MAXNB + i];
  __syncthreads();

  const unsigned short* gsh = gm_in - (size_t)M_TREE * H;
  // gather: wave-uniform indices -> SALU addressing; 4 bonds/iter = 40 loads in flight
  for (int lb = wave * 4; lb < TB; lb += 16) {
    unsigned int u[4][MAXNB];
#pragma unroll
    for (int p = 0; p < 4; ++p) {
      const int* ig = &sBG[(lb + p) * MAXNB];
#pragma unroll
      for (int j = 0; j < MAXNB; ++j) {
        int idx = __builtin_amdgcn_readfirstlane(ig[j]);
        const unsigned short* r = ((idx < M_TREE) ? tmsg : gsh) + (size_t)idx * H;
        u[p][j] = *(const unsigned int*)(r + 2 * lane);
      }
    }
#pragma unroll
    for (int p = 0; p < 4; ++p) {
      float a0 = 0.f, a1 = 0.f;
#pragma unroll
      for (int j = 0; j < MAXNB; ++j) {
        a0 += __uint_as_float(u[p][j] << 16);
        a1 += __uint_as_float(u[p][j] & 0xFFFF0000u);
      }
      unsigned int packed = ((unsigned int)f32_to_bf16(a1) << 16) | (unsigned int)f32_to_bf16(a0);
      *(unsigned int*)&snei[lb + p][2 * lane] = packed;
    }
  }

  // W_h^T fragments (after gather to limit register overlap): 32 VGPRs
  bf16x8 Bf[4][2];
#pragma unroll
  for (int kt = 0; kt < 4; ++kt)
#pragma unroll
    for (int nt = 0; nt < 2; ++nt)
      Bf[kt][nt] = *(const bf16x8*)(whb + ((wave * 2 + nt) * 16 + n16) * H + kt * 32 + quad * 8);
  __syncthreads();

  f32x4 acc[4][2];
  f32x4 zero = {0.f, 0.f, 0.f, 0.f};
#pragma unroll
  for (int mt = 0; mt < 4; ++mt) { acc[mt][0] = zero; acc[mt][1] = zero; }
#pragma unroll
  for (int kt = 0; kt < 4; ++kt)
#pragma unroll
    for (int mt = 0; mt < 4; ++mt) {
      bf16x8 av = *(const bf16x8*)&snei[mt * 16 + n16][kt * 32 + quad * 8];
      acc[mt][0] = __builtin_amdgcn_mfma_f32_16x16x32_bf16(av, Bf[kt][0], acc[mt][0], 0, 0, 0);
      acc[mt][1] = __builtin_amdgcn_mfma_f32_16x16x32_bf16(av, Bf[kt][1], acc[mt][1], 0, 0, 0);
    }
  __syncthreads();   // all MFMA reads of snei done

  // stage acc -> snei as bf16
#pragma unroll
  for (int mt = 0; mt < 4; ++mt)
#pragma unroll
    for (int nt = 0; nt < 2; ++nt) {
      const int col = (wave * 2 + nt) * 16 + n16;
#pragma unroll
      for (int r = 0; r < 4; ++r)
        snei[mt * 16 + quad * 4 + r][col] = f32_to_bf16(acc[mt][nt][r]);
    }
  __syncthreads();

  // vectorized epilogue: 64 rows x 16 chunks = 1024 -> 4/thread
  const size_t gbase = (size_t)b0 * H;
#pragma unroll
  for (int c = 0; c < 4; ++c) {
    int fl = c * 256 + t;
    int row = fl >> 4;
    int col = (fl & 15) * 8;
    u32x4 a4 = *(const u32x4*)&snei[row][col];
    u32x4 h4 = *(const u32x4*)(h0 + gbase + (size_t)row * H + col);
    u32x4 o4;
    o4.x = bfpair_addrelu(a4.x, h4.x);
    o4.y = bfpair_addrelu(a4.y, h4.y);
    o4.z = bfpair_addrelu(a4.z, h4.z);
    o4.w = bfpair_addrelu(a4.w, h4.w);
    *(u32x4*)(gm_out + gbase + (size_t)row * H + col) = o4;
  }
}

// ---- readout: 64 atoms (2 mols)/block, MFMA over K=192, 5 blocks/CU ----
__global__ __launch_bounds__(256, 5) void readout(const float* __restrict__ atom_feats,
                                                  const unsigned short* __restrict__ gm,
                                                  const unsigned short* __restrict__ tmsg,
                                                  const int* __restrict__ atom_graph,
                                                  const unsigned short* __restrict__ wob,
                                                  const float* __restrict__ b_o,
                                                  float* __restrict__ out) {
  __shared__ unsigned short sA[TA][200];     // 25600 B
  __shared__ int sAG[TA * MAXNB];            //  2560 B
  const int t = threadIdx.x;
  const int lane = t & 63;
  const int wave = t >> 6;
  const int n16 = lane & 15;
  const int quad = lane >> 4;
  const int blk = blockIdx.x;
  const int abase = blk * TA;

  for (int i = t; i < TA * MAXNB; i += 256)
    sAG[i] = __builtin_nontemporal_load(atom_graph + abase * MAXNB + i);
  for (int i = t; i < TA * FATOM; i += 256) {
    int a = i / FATOM, f = i - a * FATOM;
    sA[a][f] = f32_to_bf16(__builtin_nontemporal_load(atom_feats + abase * FATOM + i));
  }
  if (t < TA) sA[t][35] = 0;
  for (int i = t; i < TA * 28; i += 256) {
    int a = i / 28, c = 164 + i - a * 28;
    sA[a][c] = 0;
  }
  __syncthreads();

  const unsigned short* gsh = gm - (size_t)M_TREE * H;
  for (int la = wave * 2; la < TA; la += 8) {
    unsigned int u[2][MAXNB];
#pragma unroll
    for (int p = 0; p < 2; ++p) {
      const int* ig = &sAG[(la + p) * MAXNB];
#pragma unroll
      for (int j = 0; j < MAXNB; ++j) {
        int idx = __builtin_amdgcn_readfirstlane(ig[j]);
        const unsigned short* r = ((idx < M_TREE) ? tmsg : gsh) + (size_t)idx * H;
        u[p][j] = *(const unsigned int*)(r + 2 * lane);
      }
    }
#pragma unroll
    for (int p = 0; p < 2; ++p) {
      float a0 = 0.f, a1 = 0.f;
#pragma unroll
      for (int j = 0; j < MAXNB; ++j) {
        a0 += __uint_as_float(u[p][j] << 16);
        a1 += __uint_as_float(u[p][j] & 0xFFFF0000u);
      }
      unsigned int packed = ((unsigned int)f32_to_bf16(a1) << 16) | (unsigned int)f32_to_bf16(a0);
      *(unsigned int*)&sA[la + p][36 + 2 * lane] = packed;
    }
  }

  bf16x8 Bf[6][2];
#pragma unroll
  for (int kt = 0; kt < 6; ++kt)
#pragma unroll
    for (int nt = 0; nt < 2; ++nt)
      Bf[kt][nt] = *(const bf16x8*)(wob + ((wave * 2 + nt) * 16 + n16) * KPAD + kt * 32 + quad * 8);
  __syncthreads();

  f32x4 acc[4][2];
  f32x4 zero = {0.f, 0.f, 0.f, 0.f};
#pragma unroll
  for (int mt = 0; mt < 4; ++mt) { acc[mt][0] = zero; acc[mt][1] = zero; }
#pragma unroll
  for (int kt = 0; kt < 6; ++kt)
#pragma unroll
    for (int mt = 0; mt < 4; ++mt) {
      bf16x8 av = *(const bf16x8*)&sA[mt * 16 + n16][kt * 32 + quad * 8];
      acc[mt][0] = __builtin_amdgcn_mfma_f32_16x16x32_bf16(av, Bf[kt][0], acc[mt][0], 0, 0, 0);
      acc[mt][1] = __builtin_amdgcn_mfma_f32_16x16x32_bf16(av, Bf[kt][1], acc[mt][1], 0, 0, 0);
    }

  float bo[2] = { b_o[(wave * 2) * 16 + n16], b_o[(wave * 2 + 1) * 16 + n16] };
  float part[2][2] = {{0.f,0.f},{0.f,0.f}};
#pragma unroll
  for (int mt = 0; mt < 4; ++mt)
#pragma unroll
    for (int nt = 0; nt < 2; ++nt)
#pragma unroll
      for (int r = 0; r < 4; ++r)
        part[mt >> 1][nt] += fmaxf(acc[mt][nt][r] + bo[nt], 0.f);
#pragma unroll
  for (int mol = 0; mol < 2; ++mol)
#pragma unroll
    for (int nt = 0; nt < 2; ++nt) {
      float p = part[mol][nt];
      p += __shfl_xor(p, 16);
      p += __shfl_xor(p, 32);
      if (lane < 16)
        out[(blk * 2 + mol) * H + (wave * 2 + nt) * 16 + lane] = p * (1.0f / APM);
    }
}

extern "C" void kernel_launch(void* const* d_in, const int* in_sizes, int n_in,
                              void* d_out, int out_size, void* d_ws, size_t ws_size,
                              hipStream_t stream) {
  (void)in_sizes; (void)n_in; (void)out_size; (void)ws_size;
  const float* atom_feats   = (const float*)d_in[0];
  const float* bond_feats   = (const float*)d_in[1];
  const float* tree_message = (const float*)d_in[2];
  const int*   atom_graph   = (const int*)d_in[3];
  const int*   bond_graph   = (const int*)d_in[4];
  const float* W_i = (const float*)d_in[6];
  const float* W_h = (const float*)d_in[7];
  const float* W_o = (const float*)d_in[8];
  const float* b_o = (const float*)d_in[9];
  float* out = (float*)d_out;

  char* ws = (char*)d_ws;
  unsigned short* tmsg = (unsigned short*)(ws);                    //  8,388,608 B
  unsigned short* whb  = (unsigned short*)(ws + 8388608);
  unsigned short* wob  = (unsigned short*)(ws + 8421376);
  unsigned short* wib  = (unsigned short*)(ws + 8470528);
  unsigned short* h0   = (unsigned short*)(ws + 8486912);          // 67,108,864 B
  unsigned short* gm0  = (unsigned short*)(ws + 75595776);
  unsigned short* gm1  = (unsigned short*)(ws + 142704640);

  prep<<<4288, 256, 0, stream>>>(tree_message, W_h, W_o, W_i, tmsg, whb, wob, wib);
  wi_gemm<<<NBOND / 128, 256, 0, stream>>>(bond_feats, wib, h0);
  mp_step<<<NBOND / TB, 256, 0, stream>>>(h0,  gm0, h0, tmsg, bond_graph, whb);
  mp_step<<<NBOND / TB, 256, 0, stream>>>(gm0, gm1, h0, tmsg, bond_graph, whb);
  mp_step<<<NBOND / TB, 256, 0, stream>>>(gm1, gm0, h0, tmsg, bond_graph, whb);
  mp_step<<<NBOND / TB, 256, 0, stream>>>(gm0, gm1, h0, tmsg, bond_graph, whb);
  mp_step<<<NBOND / TB, 256, 0, stream>>>(gm1, gm0, h0, tmsg, bond_graph, whb);
  readout<<<NATOM / TA, 256, 0, stream>>>(atom_feats, gm0, tmsg, atom_graph, wob, b_o, out);
}